// Round 1
// baseline (4131.454 us; speedup 1.0000x reference)
//
#include <hip/hip_runtime.h>

#define N_NODES 100000
#define N_EDGES 1600000
#define D_NODE 128
#define D_EDGE 128
#define HIDDEN 256
#define D_OUT 128
#define BM 32   // nodes per MLP block; 100000 = 3125 * 32 exactly

// ---------------------------------------------------------------------------
// Kernel 1: zero the scatter-sum buffer (aliased onto d_out) and the counts.
// d_out / d_ws are re-poisoned to 0xAA before every launch, so this must run
// every call.
// ---------------------------------------------------------------------------
__global__ __launch_bounds__(256) void zero_kernel(float4* __restrict__ sums4,
                                                   float* __restrict__ counts) {
    const int n4 = N_NODES * D_EDGE / 4;  // 3,200,000 float4s
    int idx = blockIdx.x * 256 + threadIdx.x;
    if (idx < n4) sums4[idx] = make_float4(0.f, 0.f, 0.f, 0.f);
    int c = idx - n4;
    if (c >= 0 && c < N_NODES) counts[c] = 0.f;
}

// ---------------------------------------------------------------------------
// Kernel 2: scatter-add edge_attr into sums (= d_out) via fp32 atomics.
// One edge handled by 32 threads (float4 each) -> coalesced 512B row reads.
// ---------------------------------------------------------------------------
__global__ __launch_bounds__(256) void scatter_kernel(const float* __restrict__ edge_attr,
                                                      const int* __restrict__ col,
                                                      float* sums,
                                                      float* counts) {
    int gid = blockIdx.x * 256 + threadIdx.x;   // max 51.2M < 2^31
    int e = gid >> 5;
    int q = gid & 31;
    if (e >= N_EDGES) return;
    float4 v = *(const float4*)(edge_attr + e * D_EDGE + q * 4);
    int node = col[e];
    float* dst = sums + node * D_EDGE + q * 4;
    atomicAdd(dst + 0, v.x);
    atomicAdd(dst + 1, v.y);
    atomicAdd(dst + 2, v.z);
    atomicAdd(dst + 3, v.w);
    if (q == 0) atomicAdd(counts + node, 1.0f);
}

// ---------------------------------------------------------------------------
// Fused 3-layer MLP. Block = 256 threads, BM=32 nodes.
// Thread (f0 = t&63, g = t>>6) computes 8 nodes (m = g*8..g*8+7) x NJ output
// features (f = f0 + j*64). A-operand broadcast-read from LDS as float4
// (same addr across lanes -> conflict-free); W streamed from global
// (655 KB total -> L2-resident across all blocks).
// ---------------------------------------------------------------------------
template <int NJ>
__device__ __forceinline__ void gemm_layer(const float (*IN)[256],
                                           const float* __restrict__ W,
                                           const float* __restrict__ bias,
                                           int f0, int g, float (&acc)[8][NJ]) {
    constexpr int FOUT = NJ * 64;
#pragma unroll
    for (int mm = 0; mm < 8; ++mm)
#pragma unroll
        for (int j = 0; j < NJ; ++j) acc[mm][j] = bias[f0 + j * 64];

#pragma unroll 2
    for (int k = 0; k < 256; k += 4) {
        float w[4][NJ];
#pragma unroll
        for (int kk = 0; kk < 4; ++kk)
#pragma unroll
            for (int j = 0; j < NJ; ++j)
                w[kk][j] = W[(k + kk) * FOUT + f0 + j * 64];  // coalesced
#pragma unroll
        for (int mm = 0; mm < 8; ++mm) {
            float4 a = *(const float4*)(&IN[g * 8 + mm][k]);  // LDS broadcast
#pragma unroll
            for (int j = 0; j < NJ; ++j) {
                acc[mm][j] = fmaf(a.x, w[0][j], acc[mm][j]);
                acc[mm][j] = fmaf(a.y, w[1][j], acc[mm][j]);
                acc[mm][j] = fmaf(a.z, w[2][j], acc[mm][j]);
                acc[mm][j] = fmaf(a.w, w[3][j], acc[mm][j]);
            }
        }
    }
}

__global__ __launch_bounds__(256, 2) void mlp_kernel(
    const float* __restrict__ x, const float* sums, const float* __restrict__ counts,
    const float* __restrict__ W1, const float* __restrict__ b1,
    const float* __restrict__ W2, const float* __restrict__ b2,
    const float* __restrict__ W3, const float* __restrict__ b3, float* out) {
    __shared__ float A[BM][256];  // activations (in / h2)
    __shared__ float H[BM][256];  // h1
    const int block0 = blockIdx.x * BM;
    const int t = threadIdx.x;
    const int f0 = t & 63;
    const int g = t >> 6;

    // Stage concat([x, mean]) for BM nodes into LDS. sums aliases out, so all
    // reads of this block's rows happen before any write (barrier below).
    for (int i = t; i < BM * 64; i += 256) {
        int m = i >> 6;
        int q = i & 63;
        int node = block0 + m;
        float4 v = make_float4(0.f, 0.f, 0.f, 0.f);
        if (node < N_NODES) {
            if (q < 32) {
                v = *(const float4*)(x + node * D_NODE + q * 4);
            } else {
                float inv = 1.0f / fmaxf(counts[node], 1.0f);
                float4 s = *(const float4*)(sums + node * D_EDGE + (q - 32) * 4);
                v.x = s.x * inv; v.y = s.y * inv; v.z = s.z * inv; v.w = s.w * inv;
            }
        }
        *(float4*)(&A[m][q * 4]) = v;
    }
    __syncthreads();

    {  // layer 1: A(256) -> H(256), ReLU
        float acc[8][4];
        gemm_layer<4>(A, W1, b1, f0, g, acc);
#pragma unroll
        for (int mm = 0; mm < 8; ++mm)
#pragma unroll
            for (int j = 0; j < 4; ++j)
                H[g * 8 + mm][f0 + j * 64] = fmaxf(acc[mm][j], 0.0f);
    }
    __syncthreads();

    {  // layer 2: H(256) -> A(256), ReLU (A fully consumed before this barrier)
        float acc[8][4];
        gemm_layer<4>(H, W2, b2, f0, g, acc);
#pragma unroll
        for (int mm = 0; mm < 8; ++mm)
#pragma unroll
            for (int j = 0; j < 4; ++j)
                A[g * 8 + mm][f0 + j * 64] = fmaxf(acc[mm][j], 0.0f);
    }
    __syncthreads();

    {  // layer 3: A(256) -> out(128), no activation
        float acc[8][2];
        gemm_layer<2>(A, W3, b3, f0, g, acc);
#pragma unroll
        for (int mm = 0; mm < 8; ++mm) {
            int node = block0 + g * 8 + mm;
            if (node < N_NODES) {
                out[node * D_OUT + f0] = acc[mm][0];
                out[node * D_OUT + f0 + 64] = acc[mm][1];
            }
        }
    }
}

// ---------------------------------------------------------------------------
extern "C" void kernel_launch(void* const* d_in, const int* in_sizes, int n_in,
                              void* d_out, int out_size, void* d_ws, size_t ws_size,
                              hipStream_t stream) {
    const float* x         = (const float*)d_in[0];
    const int*   edge_idx  = (const int*)d_in[1];
    const float* edge_attr = (const float*)d_in[2];
    const float* W1 = (const float*)d_in[3];
    const float* b1 = (const float*)d_in[4];
    const float* W2 = (const float*)d_in[5];
    const float* b2 = (const float*)d_in[6];
    const float* W3 = (const float*)d_in[7];
    const float* b3 = (const float*)d_in[8];

    float* out    = (float*)d_out;
    float* sums   = out;              // d_out doubles as the scatter-sum buffer
    float* counts = (float*)d_ws;     // 100K floats = 400 KB of ws
    const int* col = edge_idx + N_EDGES;  // edge_index[1][:]

    {   // zero sums + counts
        const int total = N_NODES * D_EDGE / 4 + N_NODES;
        zero_kernel<<<(total + 255) / 256, 256, 0, stream>>>((float4*)sums, counts);
    }
    {   // scatter-add
        const int total = N_EDGES * 32;
        scatter_kernel<<<total / 256, 256, 0, stream>>>(edge_attr, col, sums, counts);
    }
    {   // fused MLP (reads sums in-place, writes out)
        mlp_kernel<<<(N_NODES + BM - 1) / BM, 256, 0, stream>>>(
            x, sums, counts, W1, b1, W2, b2, W3, b3, out);
    }
}